// Round 10
// baseline (172.910 us; speedup 1.0000x reference)
//
#include <hip/hip_runtime.h>
#include <math.h>

#define BB 512
#define DD 512
#define KK 93431
#define KPAD 93440

#define S_SCALEf 64.0f
#define COS_Mf   0.87758256189037276f   /* cos(0.5) */
#define SIN_Mf   0.47942553860420301f   /* sin(0.5) */
#define THRESHf (-0.87758256189037276f) /* cos(pi-0.5) */
#define MMf      0.23971276930210151f   /* sin(pi-0.5)*0.5 */
#define EPSf     0.1f
#define MFIXf    65.0f

typedef __bf16 bf16x8 __attribute__((ext_vector_type(8)));
typedef float  f32x4  __attribute__((ext_vector_type(4)));
typedef unsigned int uint32x4 __attribute__((ext_vector_type(4)));

__device__ __forceinline__ unsigned short f2bf(float f) {
    union { float f; unsigned u; } v; v.f = f;
    unsigned r = v.u + 0x7FFFu + ((v.u >> 16) & 1u);   // RNE
    return (unsigned short)(r >> 16);
}

__device__ __forceinline__ void gload16(const void* g, void* l) {
    __builtin_amdgcn_global_load_lds(
        (const __attribute__((address_space(1))) unsigned int*)g,
        (__attribute__((address_space(3))) unsigned int*)l, 16, 0, 0);
}
__device__ __forceinline__ void gload4(const void* g, void* l) {
    __builtin_amdgcn_global_load_lds(
        (const __attribute__((address_space(1))) unsigned int*)g,
        (__attribute__((address_space(3))) unsigned int*)l, 4, 0, 0);
}

// ---------------- kernel 1: row-normalize x -> xn (f32) + xnb (bf16) ----------------
__global__ void rownorm_k(const float* __restrict__ x, float* __restrict__ xn,
                          unsigned short* __restrict__ xnb) {
    int b = blockIdx.x;
    int t = threadIdx.x; // 256
    float v0 = x[b * DD + t];
    float v1 = x[b * DD + t + 256];
    float ss = v0 * v0 + v1 * v1;
    for (int off = 32; off; off >>= 1) ss += __shfl_down(ss, off);
    __shared__ float wred[4];
    __shared__ float s_inv;
    if ((t & 63) == 0) wred[t >> 6] = ss;
    __syncthreads();
    if (t == 0) s_inv = rsqrtf(wred[0] + wred[1] + wred[2] + wred[3]);
    __syncthreads();
    float inv = s_inv;
    float a0 = v0 * inv, a1 = v1 * inv;
    xn[b * DD + t]        = a0;
    xn[b * DD + t + 256]  = a1;
    xnb[b * DD + t]       = f2bf(a0);
    xnb[b * DD + t + 256] = f2bf(a1);
}

// ------ kernel 2: target logits (label columns, fp32, self-computed col norm) ------
__global__ void target_k(const float* __restrict__ xn, const float* __restrict__ ker,
                         const int* __restrict__ label, float* __restrict__ tl) {
    int b = blockIdx.x;
    int lane = threadIdx.x; // 64
    int col = label[b];
    float acc = 0.f, ss = 0.f;
#pragma unroll
    for (int d = lane; d < DD; d += 64) {
        float v = ker[(size_t)d * KK + col];
        acc = fmaf(xn[b * DD + d], v, acc);
        ss  = fmaf(v, v, ss);
    }
    for (int off = 32; off; off >>= 1) {
        acc += __shfl_down(acc, off);
        ss  += __shfl_down(ss, off);
    }
    if (lane == 0) {
        float c = acc * rsqrtf(ss);
        c = fminf(1.f, fmaxf(-1.f, c));
        tl[b] = c;
    }
}

// ---------- kernel 3: scalars (t_new, cos_theta_m, final target) ----------
__global__ void scalar_k(const float* __restrict__ tl, const float* __restrict__ t_in,
                         float* __restrict__ ctm, float* __restrict__ ftl,
                         float* __restrict__ tnew) {
    int t = threadIdx.x; // 512
    float v = tl[t];
    __shared__ float red[8];
    __shared__ float s_tn;
    float s = v;
    for (int off = 32; off; off >>= 1) s += __shfl_down(s, off);
    if ((t & 63) == 0) red[t >> 6] = s;
    __syncthreads();
    if (t == 0) {
        float tot = 0.f;
        for (int i = 0; i < 8; ++i) tot += red[i];
        s_tn = (tot / 512.0f) * 0.01f + 0.99f * t_in[0];
        tnew[0] = s_tn;
    }
    __syncthreads();
    float st = sqrtf(fmaxf(0.f, 1.f - v * v));
    float cm = v * COS_Mf - st * SIN_Mf;
    ctm[t] = cm;
    ftl[t] = (v > THRESHf) ? cm : (v - MMf);
}

// ---- kernel 4: fused GEMM: B staged raw fp32 from ker, transpose+convert+colnorm
//      done in-block.  128x128 tile, 16 phases of BKh=32, 2 blocks/CU. ----
#define TMt 128
#define TNt 128
#define NWG ((KPAD / TNt) * (BB / TMt))   /* 730 * 4 = 2920 */

__global__ __launch_bounds__(512, 4) void gemm_k(
    const unsigned short* __restrict__ xnb,    // [512][512] bf16 row-major
    const float* __restrict__ ker,             // [512][93431] fp32 row-major
    const int* __restrict__ label,
    const float* __restrict__ ctm, const float* __restrict__ ftl,
    const float* __restrict__ tnew,
    float* __restrict__ gse, float* __restrict__ gsl)
{
    __shared__ __align__(16) unsigned short As[2][TMt * 64];  // 2 x 16 KB bf16
    __shared__ __align__(16) float Bs[2][32 * 131];           // 2 x 16.75 KB fp32 (pad 131)
    __shared__ float se_s[TMt], sl_s[TMt], ctm_s[TMt], ftl_s[TMt];
    __shared__ int   lbl_s[TMt];

    // bijective XCD swizzle (2920 % 8 == 0); row-block-inner decomposition
    int wg = blockIdx.x;
    int id = (wg & 7) * (NWG / 8) + (wg >> 3);
    int by = id & 3;                   // 4 row-blocks of a col-tile adjacent (XCD L2)
    int bx = id >> 2;
    int row0 = by * TMt;
    int col0 = bx * TNt;

    const int t = threadIdx.x;         // 512
    const int lane = t & 63;
    const int w = t >> 6;
    const int wm = w >> 2;             // 0..1  (64-row slice)
    const int wn = w & 3;              // 0..3  (32-col slice)
    const int cp0 = lane & 15;
    const int kq = lane >> 4;

    if (t < TMt) {
        se_s[t] = 0.f; sl_s[t] = 0.f;
        int r = row0 + t;
        ctm_s[t] = ctm[r]; ftl_s[t] = ftl[r]; lbl_s[t] = label[r];
    }
    const float tn = tnew[0];

    // ---- staging macros ----
    // A half j (tile kt=j>>1, half h=j&1): 1 gload16/thread, verified swizzle.
#define STAGE_A_HALF(j)                                                        \
    {                                                                          \
        const int l = (((j) & 1) << 9) + t;                                    \
        const int r = l >> 3, kcs = (l & 7) ^ (r & 7);                         \
        gload16(&xnb[(size_t)(row0 + r) * DD + ((j) >> 1) * 64 + kcs * 8],     \
                (void*)&As[((j) >> 1) & 1][l * 8]);                            \
    }
    // B phase q: 32 d-rows x 128 cols fp32, linear d-major [32][131] (padded).
#define STAGE_B(q)                                                             \
    {                                                                          \
        const float* kb = ker + (size_t)((q) * 32) * KK + col0;                \
        float* bd = &Bs[(q) & 1][0];                                           \
        _Pragma("unroll")                                                      \
        for (int jj = 0; jj < 8; ++jj) {                                       \
            int g = w * 8 + jj;                                                \
            int dl = g >> 1, hc = g & 1;                                       \
            gload4(kb + (size_t)dl * KK + hc * 64 + lane,                      \
                   (void*)(bd + dl * 131 + hc * 64 + lane));                   \
        }                                                                      \
    }

    f32x4 acc[4][2];
#pragma unroll
    for (int fm = 0; fm < 4; ++fm)
#pragma unroll
        for (int fc = 0; fc < 2; ++fc) acc[fm][fc] = (f32x4)0.f;
    float ssqr[2] = {0.f, 0.f};

    // ---- prologue: B(0) + A(0) both halves ----
    STAGE_B(0);
    STAGE_A_HALF(0);
    STAGE_A_HALF(1);
    __builtin_amdgcn_sched_barrier(0);
    asm volatile("s_waitcnt vmcnt(0)" ::: "memory");
    __builtin_amdgcn_s_barrier();

    // ---- 16 phases; B staged 1-ahead (other buffer), A tile kt+1 staged at
    //      even phase 2kt (into buffer (kt+1)&1, not being read). Gates:
    //      even p<=12: vmcnt(2) (A pair may fly), else vmcnt(0). ----
#pragma unroll
    for (int p = 0; p < 16; ++p) {
        if (p <= 14) STAGE_B(p + 1);
        if ((p & 1) == 0 && p >= 2 && p <= 12) {
            STAGE_A_HALF(p + 2);   // tile p/2+1, buf (p/2+1)&1 != read buf
            STAGE_A_HALF(p + 3);
        }
        if (p == 0) { STAGE_A_HALF(2); STAGE_A_HALF(3); }  // tile 1

        // ---- compute phase p ----
        const int kt = p >> 1, h = p & 1;
        const char* Ap = (const char*)&As[kt & 1][0];
        const float* Bb = &Bs[p & 1][0];

        bf16x8 bfr[2];
#pragma unroll
        for (int fc = 0; fc < 2; ++fc) {
            const int cb = wn * 32 + fc * 16 + cp0;
            float sv[8];
#pragma unroll
            for (int i = 0; i < 8; ++i) sv[i] = Bb[(kq * 8 + i) * 131 + cb];
            unsigned pk[4];
#pragma unroll
            for (int i2 = 0; i2 < 4; ++i2) {
                asm("v_cvt_pk_bf16_f32 %0, %1, %2"
                    : "=v"(pk[i2]) : "v"(sv[2 * i2]), "v"(sv[2 * i2 + 1]));
                ssqr[fc] = fmaf(sv[2 * i2], sv[2 * i2], ssqr[fc]);
                ssqr[fc] = fmaf(sv[2 * i2 + 1], sv[2 * i2 + 1], ssqr[fc]);
            }
            uint32x4 u = {pk[0], pk[1], pk[2], pk[3]};
            bfr[fc] = __builtin_bit_cast(bf16x8, u);
        }
#pragma unroll
        for (int fm = 0; fm < 4; ++fm) {
            const int rt = wm * 64 + fm * 16 + cp0;
            bf16x8 af = *reinterpret_cast<const bf16x8*>(
                Ap + rt * 128 + (((h * 4 + kq) ^ (rt & 7)) * 16));
            acc[fm][0] = __builtin_amdgcn_mfma_f32_16x16x32_bf16(
                af, bfr[0], acc[fm][0], 0, 0, 0);
            acc[fm][1] = __builtin_amdgcn_mfma_f32_16x16x32_bf16(
                af, bfr[1], acc[fm][1], 0, 0, 0);
        }

        if (p < 15) {
            __builtin_amdgcn_sched_barrier(0);
            if ((p & 1) == 0 && p <= 12)
                asm volatile("s_waitcnt vmcnt(2)" ::: "memory");  // B(p+1) landed, A pair flies
            else
                asm volatile("s_waitcnt vmcnt(0)" ::: "memory");
            __builtin_amdgcn_s_barrier();
        }
    }
#undef STAGE_A_HALF
#undef STAGE_B

    // ---- in-block column norms: reduce ssq partials across the 4 kq groups ----
#pragma unroll
    for (int fc = 0; fc < 2; ++fc) {
        ssqr[fc] += __shfl_xor(ssqr[fc], 16);
        ssqr[fc] += __shfl_xor(ssqr[fc], 32);
    }
    float inv2[2] = { rsqrtf(ssqr[0]), rsqrtf(ssqr[1]) };

    // ---- fused CurricularFace epilogue (full-K acc; NaN-safe pad masking) ----
#pragma unroll
    for (int fm = 0; fm < 4; ++fm) {
#pragma unroll
        for (int reg = 0; reg < 4; ++reg) {
            const int rt = wm * 64 + fm * 16 + (kq << 2) + reg;  // block-local row
            float cm = ctm_s[rt], ft = ftl_s[rt];
            const int rel = lbl_s[rt] - (col0 + wn * 32 + cp0);
            float se = 0.f, sl = 0.f;
#pragma unroll
            for (int fc = 0; fc < 2; ++fc) {
                const int gc = col0 + wn * 32 + fc * 16 + cp0;
                float c = acc[fm][fc][reg] * inv2[fc];
                c = fminf(1.f, fmaxf(-1.f, c));
                float v = (c > cm) ? c * (tn + c) : c;
                if (rel == fc * 16) v = ft;
                float lg = S_SCALEf * v;
                float e = __expf(lg - MFIXf);
                if (gc >= KK) { e = 0.f; lg = 0.f; }   // pad cols: select, NaN-safe
                se += e;
                sl += lg;
            }
#pragma unroll
            for (int off = 8; off; off >>= 1) {
                se += __shfl_down(se, off, 16);
                sl += __shfl_down(sl, off, 16);
            }
            if (cp0 == 0) {
                atomicAdd(&se_s[rt], se);
                atomicAdd(&sl_s[rt], sl);
            }
        }
    }
    __syncthreads();
    if (t < TMt) {
        atomicAdd(&gse[row0 + t], se_s[t]);
        atomicAdd(&gsl[row0 + t], sl_s[t]);
    }
}

// ---------------- kernel 5: final loss ----------------
__global__ void loss_k(const float* __restrict__ gse, const float* __restrict__ gsl,
                       const float* __restrict__ ftl, float* __restrict__ out) {
    int t = threadIdx.x; // 512
    float lse = MFIXf + logf(gse[t]);
    float lbl_logit = S_SCALEf * ftl[t];
    float nll = (1.f - EPSf) * (lbl_logit - lse)
              + (EPSf / (float)KK) * (gsl[t] - (float)KK * lse);
    __shared__ float red[8];
    float s = nll;
    for (int off = 32; off; off >>= 1) s += __shfl_down(s, off);
    if ((t & 63) == 0) red[t >> 6] = s;
    __syncthreads();
    if (t == 0) {
        float tot = 0.f;
        for (int i = 0; i < 8; ++i) tot += red[i];
        out[0] = -(tot / 512.0f);
    }
}

extern "C" void kernel_launch(void* const* d_in, const int* in_sizes, int n_in,
                              void* d_out, int out_size, void* d_ws, size_t ws_size,
                              hipStream_t stream) {
    const float* x     = (const float*)d_in[0];
    const int*   label = (const int*)d_in[1];
    const float* ker   = (const float*)d_in[2];
    const float* t_in  = (const float*)d_in[3];
    float* out = (float*)d_out;

    float* ws   = (float*)d_ws;
    float* xn   = ws;                 // 262144 f32
    float* gse  = xn + 262144;        // 512
    float* gsl  = gse + 512;          // 512
    float* tl   = gsl + 512;          // 512
    float* ctm  = tl + 512;           // 512
    float* ftl  = ctm + 512;          // 512
    float* tnew = ftl + 512;          // 64
    unsigned short* xnb = (unsigned short*)(tnew + 64);      // 262144 bf16

    hipMemsetAsync(gse, 0, 1024 * sizeof(float), stream);

    rownorm_k<<<BB, 256, 0, stream>>>(x, xn, xnb);
    target_k<<<BB, 64, 0, stream>>>(xn, ker, label, tl);
    scalar_k<<<1, 512, 0, stream>>>(tl, t_in, ctm, ftl, tnew);
    gemm_k<<<NWG, 512, 0, stream>>>(xnb, ker, label, ctm, ftl, tnew, gse, gsl);
    loss_k<<<1, 512, 0, stream>>>(gse, gsl, ftl, out);
}